// Round 10
// baseline (102.224 us; speedup 1.0000x reference)
//
#include <hip/hip_runtime.h>

typedef short bf16x8 __attribute__((ext_vector_type(8)));
typedef float f32x4  __attribute__((ext_vector_type(4)));
typedef unsigned short ushort_t;

#define HID 32
#define CC  64
#define TT  8
#define NN  1024
#define BB  4
#define KTOT 8192
#define NKC_A 16               // k-chunks for k_att2; KCHUNK_A=512 (single t per chunk)
#define KCHUNK_A (KTOT/NKC_A)  // 512
#define NKC_P 32               // k-chunks for k_psum; KCHUNK_P=256
#define KCHUNK_P (KTOT/NKC_P)  // 256

// f32 -> bf16 (RNE)
__device__ __forceinline__ ushort_t f2b(float x) {
    unsigned int u = __float_as_uint(x);
    return (ushort_t)((u + 0x7fffu + ((u >> 16) & 1u)) >> 16);
}
__device__ __forceinline__ float b2f(ushort_t u) {
    return __uint_as_float((unsigned int)u << 16);
}

// --- K1 fused: blocks 0..255 -> hkT planes + hkDB;  blocks 256..271 -> hq hi/lo ---
__global__ __launch_bounds__(256) void k_pre(const float* __restrict__ H,
                                             const float* __restrict__ h,
                                             const float* __restrict__ wq,
                                             const float* __restrict__ wkv,
                                             ushort_t* __restrict__ hqHI,
                                             ushort_t* __restrict__ hqLO,
                                             ushort_t* __restrict__ hkTH0,
                                             ushort_t* __restrict__ hkTH1,
                                             ushort_t* __restrict__ hkTL0,
                                             ushort_t* __restrict__ hkTL1,
                                             ushort_t* __restrict__ hkDB) {
    int bx = blockIdx.x;
    if (bx < 256) {
        // H_kv: hi/lo k-major planes (16-wide) + d-major bf16
        int gid = bx * 256 + threadIdx.x;          // 0..65535
        int dg = gid >> 15;                        // block-uniform d-half
        int rest = gid & 32767;
        int b = rest >> 13, tn = rest & 8191;
        int d0 = dg << 4;
        float acc[16];
#pragma unroll
        for (int d = 0; d < 16; d++) acc[d] = 0.f;
        const float* Hb = H + (size_t)(b * CC) * KTOT + tn;
        const float* wb = wkv + d0 * CC;
#pragma unroll 16
        for (int c = 0; c < CC; c++) {
            float v = Hb[(size_t)c * KTOT];        // coalesced
#pragma unroll
            for (int d = 0; d < 16; d++) acc[d] += wb[d * CC + c] * v;  // uniform -> s_load
        }
        ushort_t thi[16], tlo[16];
#pragma unroll
        for (int d = 0; d < 16; d++) {
            ushort_t hi = f2b(acc[d]);
            thi[d] = hi;
            tlo[d] = f2b(acc[d] - b2f(hi));
        }
        size_t po = ((size_t)b * KTOT + tn) * 16;
        bf16x8* ohi = (bf16x8*)((dg ? hkTH1 : hkTH0) + po);
        bf16x8* olo = (bf16x8*)((dg ? hkTL1 : hkTL0) + po);
#pragma unroll
        for (int v8 = 0; v8 < 2; v8++) {
            bf16x8 a, l;
#pragma unroll
            for (int j = 0; j < 8; j++) { a[j] = (short)thi[v8*8+j]; l[j] = (short)tlo[v8*8+j]; }
            ohi[v8] = a; olo[v8] = l;
        }
#pragma unroll
        for (int d = 0; d < 16; d++)
            hkDB[((size_t)(b * HID) + d0 + d) * KTOT + tn] = thi[d];   // coalesced per d
    } else {
        // h_q hi/lo, layout [b*N+n][32]
        int gid = (bx - 256) * 256 + threadIdx.x;  // 0..4095
        int b = gid >> 10;
        float acc[HID];
#pragma unroll
        for (int d = 0; d < HID; d++) acc[d] = 0.f;
        const float* hb = h + (size_t)(b * CC) * NN + (gid & 1023);
#pragma unroll 8
        for (int c = 0; c < CC; c++) {
            float v = hb[c * NN];                  // coalesced
#pragma unroll
            for (int d = 0; d < HID; d++) acc[d] += wq[d * CC + c] * v;
        }
        bf16x8* ohi = (bf16x8*)(hqHI + (size_t)gid * HID);
        bf16x8* olo = (bf16x8*)(hqLO + (size_t)gid * HID);
#pragma unroll
        for (int v8 = 0; v8 < 4; v8++) {
            bf16x8 thi, tlo;
#pragma unroll
            for (int j = 0; j < 8; j++) {
                float x = acc[v8 * 8 + j];
                ushort_t hi = f2b(x);
                thi[j] = (short)hi;
                tlo[j] = (short)f2b(x - b2f(hi));
            }
            ohi[v8] = thi; olo[v8] = tlo;
        }
    }
}

// ---- Pass A: psum[b][kc][m] over 256-row chunks. 2048 blocks x 256 thr, 8 waves/SIMD ----
__global__ __launch_bounds__(256, 8) void k_psum(const ushort_t* __restrict__ hqHI,
                                                 const ushort_t* __restrict__ hqLO,
                                                 const ushort_t* __restrict__ hkTH0,
                                                 const ushort_t* __restrict__ hkTH1,
                                                 const ushort_t* __restrict__ hkTL0,
                                                 const ushort_t* __restrict__ hkTL1,
                                                 float* __restrict__ psum) {
    int bx = blockIdx.x;                           // 2048: b(4) x mt(16) x kc(32)
    int b = bx >> 9, mt = (bx >> 5) & 15, kc = bx & 31;
    int wave = threadIdx.x >> 6, lane = threadIdx.x & 63;
    int g = lane >> 4, c = lane & 15;
    int m = mt * 64 + wave * 16 + c;
    int t = kc >> 2;
    int nb0 = (kc & 3) << 8;                       // chunk covers n in [nb0, nb0+256)

    // B frag: key column hkT[t,m], hi/lo, plane g>>1, offset (g&1)*8
    size_t bqo = ((size_t)b * KTOT + t * NN + m) * 16 + (g & 1) * 8;
    bf16x8 bqh = *(const bf16x8*)(((g >> 1) ? hkTH1 : hkTH0) + bqo);
    bf16x8 bql = *(const bf16x8*)(((g >> 1) ? hkTL1 : hkTL0) + bqo);

    const ushort_t* qhi = hqHI + ((size_t)(b << 10)) * HID;
    const ushort_t* qlo = hqLO + ((size_t)(b << 10)) * HID;

    float csum0 = 0.f, csum1 = 0.f;
    for (int s16 = 0; s16 < KCHUNK_P / 16; s16 += 2) {  // 8 iters, 2 tiles each
        int nbA = nb0 + s16 * 16;
        int nbB = nbA + 16;
        size_t aoA = (size_t)(nbA + c) * HID + 8 * g;
        size_t aoB = (size_t)(nbB + c) * HID + 8 * g;
        bf16x8 ahA = *(const bf16x8*)(qhi + aoA);
        bf16x8 alA = *(const bf16x8*)(qlo + aoA);
        bf16x8 ahB = *(const bf16x8*)(qhi + aoB);
        bf16x8 alB = *(const bf16x8*)(qlo + aoB);
        f32x4 svA = __builtin_amdgcn_mfma_f32_16x16x32_bf16(ahA, bql, (f32x4){0.f,0.f,0.f,0.f}, 0, 0, 0);
        f32x4 svB = __builtin_amdgcn_mfma_f32_16x16x32_bf16(ahB, bql, (f32x4){0.f,0.f,0.f,0.f}, 0, 0, 0);
        svA = __builtin_amdgcn_mfma_f32_16x16x32_bf16(alA, bqh, svA, 0, 0, 0);
        svB = __builtin_amdgcn_mfma_f32_16x16x32_bf16(alB, bqh, svB, 0, 0, 0);
        svA = __builtin_amdgcn_mfma_f32_16x16x32_bf16(ahA, bqh, svA, 0, 0, 0);
        svB = __builtin_amdgcn_mfma_f32_16x16x32_bf16(ahB, bqh, svB, 0, 0, 0);
        int nrowA = nbA + 4 * g;                   // D row = query n
        int nrowB = nbB + 4 * g;
#pragma unroll
        for (int r = 0; r < 4; r++) {
            float xA = (nrowA + r == m) ? 0.f : svA[r];
            float xB = (nrowB + r == m) ? 0.f : svB[r];
            csum0 += __expf(xA);
            csum1 += __expf(xB);
        }
    }
    float csum = csum0 + csum1;
    csum += __shfl_xor(csum, 16);
    csum += __shfl_xor(csum, 32);
    if (lane < 16)
        psum[(((size_t)(b * NKC_P + kc)) << 10) + mt * 64 + wave * 16 + lane] = csum;
}

// ---- Pass B: S^T orientation -> dwordx4 att stores. 1024 blocks x 256 thr ----
__global__ __launch_bounds__(256, 4) void k_att2(const ushort_t* __restrict__ hqHI,
                                                 const ushort_t* __restrict__ hqLO,
                                                 const ushort_t* __restrict__ hkTH0,
                                                 const ushort_t* __restrict__ hkTH1,
                                                 const ushort_t* __restrict__ hkTL0,
                                                 const ushort_t* __restrict__ hkTL1,
                                                 const ushort_t* __restrict__ hkDB,
                                                 const float* __restrict__ psum,
                                                 float* __restrict__ att,
                                                 float* __restrict__ hvp) {
    int bx = blockIdx.x;                           // 1024: b(4) x mt(16) x kc(16)
    int b = bx >> 8, mt = (bx >> 4) & 15, kc = bx & 15;
    int wave = threadIdx.x >> 6, lane = threadIdx.x & 63;
    int g = lane >> 4, c = lane & 15;
    int mb = mt * 64 + wave * 16;                  // wave's 16-wide m-tile
    int t = kc >> 1;
    int nb0 = (kc & 1) << 9;

    // denominators for this lane's 4 m's (m = mb + 4g + r)
    f32x4 gs = {0.f, 0.f, 0.f, 0.f};
#pragma unroll
    for (int j = 0; j < NKC_P; j++)
        gs += *(const f32x4*)(psum + (((size_t)(b * NKC_P + j)) << 10) + mb + 4 * g);
    f32x4 vinv;
#pragma unroll
    for (int r = 0; r < 4; r++) vinv[r] = 1.0f / gs[r];

    // A frag (loop-invariant): key[m = mb + c][d = 8g+j], hi/lo
    size_t ako = ((size_t)b * KTOT + t * NN + (mb + c)) * 16 + (g & 1) * 8;
    bf16x8 akh = *(const bf16x8*)(((g >> 1) ? hkTH1 : hkTH0) + ako);
    bf16x8 akl = *(const bf16x8*)(((g >> 1) ? hkTL1 : hkTL0) + ako);

    const ushort_t* qhi = hqHI + ((size_t)(b << 10)) * HID;
    const ushort_t* qlo = hqLO + ((size_t)(b << 10)) * HID;
    const ushort_t* vb0 = hkDB + (size_t)(b * HID + c) * KTOT;
    const ushort_t* vb1 = hkDB + (size_t)(b * HID + 16 + c) * KTOT;
    float* attb = att + (size_t)b * KTOT * NN;

    // per-wave P-transpose tile: PT[m-local 16][k-local 32 pad->40]
    __shared__ __align__(16) ushort_t PT[4][16][40];
    ushort_t (*pt)[40] = PT[wave];

    f32x4 acc0 = {0.f,0.f,0.f,0.f}, acc1 = {0.f,0.f,0.f,0.f};

    for (int ks = 0; ks < KCHUNK_A / 32; ks++) {   // 16 iters, 32 k each
        int k0 = kc * KCHUNK_A + ks * 32;
#pragma unroll
        for (int half = 0; half < 2; half++) {
            int nb = nb0 + ks * 32 + half * 16;    // n-tile base
            size_t qo = (size_t)(nb + c) * HID + 8 * g;
            bf16x8 qh = *(const bf16x8*)(qhi + qo);
            bf16x8 ql = *(const bf16x8*)(qlo + qo);
            // S^T[m][n] = sum_d key[m,d]*q[n,d]  (hi*lo + lo*hi + hi*hi)
            f32x4 sv = __builtin_amdgcn_mfma_f32_16x16x32_bf16(akh, ql, (f32x4){0.f,0.f,0.f,0.f}, 0, 0, 0);
            sv = __builtin_amdgcn_mfma_f32_16x16x32_bf16(akl, qh, sv, 0, 0, 0);
            sv = __builtin_amdgcn_mfma_f32_16x16x32_bf16(akh, qh, sv, 0, 0, 0);
            int n = nb + c;                        // this lane's att row (k = t*NN + n)
            float e0, e1, e2, e3;
            {
                float x0 = (n == mb + 4 * g + 0) ? 0.f : sv[0];
                float x1 = (n == mb + 4 * g + 1) ? 0.f : sv[1];
                float x2 = (n == mb + 4 * g + 2) ? 0.f : sv[2];
                float x3 = (n == mb + 4 * g + 3) ? 0.f : sv[3];
                e0 = __expf(x0) * vinv[0];
                e1 = __expf(x1) * vinv[1];
                e2 = __expf(x2) * vinv[2];
                e3 = __expf(x3) * vinv[3];
            }
            f32x4 ev; ev[0] = e0; ev[1] = e1; ev[2] = e2; ev[3] = e3;
            __builtin_nontemporal_store(ev,
                (f32x4*)(attb + (size_t)(t * NN + n) * NN + mb + 4 * g));  // 16B/lane stream
            // PT[m-local][k-local]: m-local = 4g+r, k-local = half*16 + c
            int kl = half * 16 + c;
            pt[4 * g + 0][kl] = f2b(e0);
            pt[4 * g + 1][kl] = f2b(e1);
            pt[4 * g + 2][kl] = f2b(e2);
            pt[4 * g + 3][kl] = f2b(e3);
        }
        // GEMM2: hv[m,d] += sum_k P[m,k] * V[k,d]
        bf16x8 pa = *(const bf16x8*)&pt[c][8 * g];        // A2[m=c][k=8g+j]
        bf16x8 v0 = *(const bf16x8*)(vb0 + k0 + 8 * g);   // B2[k][d=c]
        bf16x8 v1 = *(const bf16x8*)(vb1 + k0 + 8 * g);   // B2[k][d=16+c]
        acc0 = __builtin_amdgcn_mfma_f32_16x16x32_bf16(pa, v0, acc0, 0, 0, 0);
        acc1 = __builtin_amdgcn_mfma_f32_16x16x32_bf16(pa, v1, acc1, 0, 0, 0);
    }
    // hvp[b][kc][m][d]; D2 row = m-local (4g+r), col = d (c / 16+c)
    float* o = hvp + ((((size_t)(b * NKC_A + kc)) << 10) + mb) * HID;
#pragma unroll
    for (int r = 0; r < 4; r++) {
        o[(size_t)(4 * g + r) * HID + c]      = acc0[r];
        o[(size_t)(4 * g + r) * HID + 16 + c] = acc1[r];
    }
}

// ---- out0[b,c,m] = h[b,c,m] + sum_d w_o[c,d] * (sum_kc hvp[b][kc][m][d]) ----
__global__ __launch_bounds__(512) void k_out(const float* __restrict__ h,
                                             const float* __restrict__ wo,
                                             const float* __restrict__ hvp,
                                             float* __restrict__ out0) {
    int bx = blockIdx.x;                           // 256: b(4) x mt(64)
    int b = bx >> 6, mt = bx & 63;
    int m0 = mt * 16;
    int tid = threadIdx.x;
    __shared__ float hvL[16][33];
    {
        int mm = tid >> 5, d = tid & 31;           // one value per thread
        float s = 0.f;
#pragma unroll
        for (int kc = 0; kc < NKC_A; kc++)
            s += hvp[(((size_t)(b * NKC_A + kc)) << 15) + (size_t)(m0 + mm) * HID + d]; // coalesced
        hvL[mm][d] = s;
    }
    __syncthreads();
#pragma unroll
    for (int i0 = 0; i0 < 2; i0++) {
        int i = i0 * 512 + tid;
        int c = i >> 4, mm = i & 15;
        float v = h[(size_t)(b * CC + c) * NN + m0 + mm];
#pragma unroll
        for (int d = 0; d < HID; d++) v += wo[c * HID + d] * hvL[mm][d];
        out0[(size_t)(b * CC + c) * NN + m0 + mm] = v;
    }
}

extern "C" void kernel_launch(void* const* d_in, const int* in_sizes, int n_in,
                              void* d_out, int out_size, void* d_ws, size_t ws_size,
                              hipStream_t stream) {
    const float* H   = (const float*)d_in[0];
    const float* h   = (const float*)d_in[1];
    const float* wq  = (const float*)d_in[2];
    const float* wkv = (const float*)d_in[3];
    const float* wo  = (const float*)d_in[4];

    float* out0 = (float*)d_out;                       // [4,64,32,32]
    float* att  = out0 + (size_t)BB * CC * NN;         // [4,8192,1024]

    ushort_t* hqHI  = (ushort_t*)d_ws;                 // 131072
    ushort_t* hqLO  = hqHI  + 131072;                  // 131072
    ushort_t* hkTH0 = hqLO  + 131072;                  // 524288
    ushort_t* hkTH1 = hkTH0 + 524288;                  // 524288
    ushort_t* hkTL0 = hkTH1 + 524288;                  // 524288
    ushort_t* hkTL1 = hkTL0 + 524288;                  // 524288
    ushort_t* hkDB  = hkTL1 + 524288;                  // 1048576
    float* psum = (float*)(hkDB + 1048576);            // 131072 (32 chunks)
    float* hvp  = psum + 131072;                       // 2097152  (~16 MB total)

    k_pre <<<272,  256, 0, stream>>>(H, h, wq, wkv, hqHI, hqLO,
                                     hkTH0, hkTH1, hkTL0, hkTL1, hkDB);
    k_psum<<<2048, 256, 0, stream>>>(hqHI, hqLO, hkTH0, hkTH1, hkTL0, hkTL1, psum);
    k_att2<<<1024, 256, 0, stream>>>(hqHI, hqLO, hkTH0, hkTH1, hkTL0, hkTL1, hkDB,
                                     psum, att, hvp);
    k_out <<<256,  512, 0, stream>>>(h, wo, hvp, out0);
}

// Round 11
// 88.504 us; speedup vs baseline: 1.1550x; 1.1550x over previous
//
#include <hip/hip_runtime.h>

typedef short bf16x8 __attribute__((ext_vector_type(8)));
typedef float f32x4  __attribute__((ext_vector_type(4)));
typedef unsigned short ushort_t;

#define HID 32
#define CC  64
#define TT  8
#define NN  1024
#define BB  4
#define KTOT 8192

// f32 -> bf16 (RNE)
__device__ __forceinline__ ushort_t f2b(float x) {
    unsigned int u = __float_as_uint(x);
    return (ushort_t)((u + 0x7fffu + ((u >> 16) & 1u)) >> 16);
}
__device__ __forceinline__ float b2f(ushort_t u) {
    return __uint_as_float((unsigned int)u << 16);
}

// --- K1 fused: blocks 0..255 -> hkT planes + hkDB;  blocks 256..271 -> hq hi/lo ---
__global__ __launch_bounds__(256) void k_pre(const float* __restrict__ H,
                                             const float* __restrict__ h,
                                             const float* __restrict__ wq,
                                             const float* __restrict__ wkv,
                                             ushort_t* __restrict__ hqHI,
                                             ushort_t* __restrict__ hqLO,
                                             ushort_t* __restrict__ hkTH0,
                                             ushort_t* __restrict__ hkTH1,
                                             ushort_t* __restrict__ hkTL0,
                                             ushort_t* __restrict__ hkTL1,
                                             ushort_t* __restrict__ hkDB) {
    int bx = blockIdx.x;
    if (bx < 256) {
        int gid = bx * 256 + threadIdx.x;          // 0..65535
        int dg = gid >> 15;                        // block-uniform d-half
        int rest = gid & 32767;
        int b = rest >> 13, tn = rest & 8191;
        int d0 = dg << 4;
        float acc[16];
#pragma unroll
        for (int d = 0; d < 16; d++) acc[d] = 0.f;
        const float* Hb = H + (size_t)(b * CC) * KTOT + tn;
        const float* wb = wkv + d0 * CC;
#pragma unroll 8
        for (int c = 0; c < CC; c++) {
            float v = Hb[(size_t)c * KTOT];        // coalesced
#pragma unroll
            for (int d = 0; d < 16; d++) acc[d] += wb[d * CC + c] * v;  // uniform -> s_load
        }
        ushort_t thi[16], tlo[16];
#pragma unroll
        for (int d = 0; d < 16; d++) {
            ushort_t hi = f2b(acc[d]);
            thi[d] = hi;
            tlo[d] = f2b(acc[d] - b2f(hi));
        }
        size_t po = ((size_t)b * KTOT + tn) * 16;
        bf16x8* ohi = (bf16x8*)((dg ? hkTH1 : hkTH0) + po);
        bf16x8* olo = (bf16x8*)((dg ? hkTL1 : hkTL0) + po);
#pragma unroll
        for (int v8 = 0; v8 < 2; v8++) {
            bf16x8 a, l;
#pragma unroll
            for (int j = 0; j < 8; j++) { a[j] = (short)thi[v8*8+j]; l[j] = (short)tlo[v8*8+j]; }
            ohi[v8] = a; olo[v8] = l;
        }
#pragma unroll
        for (int d = 0; d < 16; d++)
            hkDB[((size_t)(b * HID) + d0 + d) * KTOT + tn] = thi[d];   // coalesced per d
    } else {
        int gid = (bx - 256) * 256 + threadIdx.x;  // 0..4095
        int b = gid >> 10;
        float acc[HID];
#pragma unroll
        for (int d = 0; d < HID; d++) acc[d] = 0.f;
        const float* hb = h + (size_t)(b * CC) * NN + (gid & 1023);
#pragma unroll 4
        for (int c = 0; c < CC; c++) {
            float v = hb[c * NN];                  // coalesced
#pragma unroll
            for (int d = 0; d < HID; d++) acc[d] += wq[d * CC + c] * v;
        }
        bf16x8* ohi = (bf16x8*)(hqHI + (size_t)gid * HID);
        bf16x8* olo = (bf16x8*)(hqLO + (size_t)gid * HID);
#pragma unroll
        for (int v8 = 0; v8 < 4; v8++) {
            bf16x8 thi, tlo;
#pragma unroll
            for (int j = 0; j < 8; j++) {
                float x = acc[v8 * 8 + j];
                ushort_t hi = f2b(x);
                thi[j] = (short)hi;
                tlo[j] = (short)f2b(x - b2f(hi));
            }
            ohi[v8] = thi; olo[v8] = tlo;
        }
    }
}

// ---- Fused: denominators (pass 1) + att + hv (pass 2), all k per block ----
// 256 blocks = b(4) x mt(64); block = 16 waves; wave w: t=w>>1, n-half=(w&1)*512.
__global__ __launch_bounds__(1024) void k_fuse(const ushort_t* __restrict__ hqHI,
                                               const ushort_t* __restrict__ hqLO,
                                               const ushort_t* __restrict__ hkTH0,
                                               const ushort_t* __restrict__ hkTH1,
                                               const ushort_t* __restrict__ hkTL0,
                                               const ushort_t* __restrict__ hkTL1,
                                               const ushort_t* __restrict__ hkDB,
                                               float* __restrict__ att,
                                               float* __restrict__ hv2) {
    int bx = blockIdx.x;
    int b = bx >> 6, mt = bx & 63;
    int mb = mt << 4;                              // 16-wide m-tile
    int tid = threadIdx.x;
    int wave = tid >> 6, lane = tid & 63;
    int g = lane >> 4, c = lane & 15;
    int t = wave >> 1;
    int nh = (wave & 1) << 9;                      // n-half base

    __shared__ float csred[16][16];                // [wave][m-local]
    __shared__ float hvred[16][16][32];            // [wave][m-local][d]
    __shared__ __align__(16) ushort_t PT[16][16][40];

    // A frag (loop-invariant): key[mb+c][d] at this t, hi/lo
    size_t ako = ((size_t)b * KTOT + t * NN + (mb + c)) * 16 + (g & 1) * 8;
    bf16x8 akh = *(const bf16x8*)(((g >> 1) ? hkTH1 : hkTH0) + ako);
    bf16x8 akl = *(const bf16x8*)(((g >> 1) ? hkTL1 : hkTL0) + ako);

    const ushort_t* qhi = hqHI + ((size_t)(b << 10)) * HID;
    const ushort_t* qlo = hqLO + ((size_t)(b << 10)) * HID;

    // ---- pass 1: exp-sum partials over this wave's (t, n-half) ----
    f32x4 cs = {0.f, 0.f, 0.f, 0.f};
    for (int s16 = 0; s16 < 32; s16 += 2) {        // 2-way ILP
        int nbA = nh + s16 * 16, nbB = nbA + 16;
        size_t aoA = (size_t)(nbA + c) * HID + 8 * g;
        size_t aoB = (size_t)(nbB + c) * HID + 8 * g;
        bf16x8 qhA = *(const bf16x8*)(qhi + aoA);
        bf16x8 qlA = *(const bf16x8*)(qlo + aoA);
        bf16x8 qhB = *(const bf16x8*)(qhi + aoB);
        bf16x8 qlB = *(const bf16x8*)(qlo + aoB);
        f32x4 svA = __builtin_amdgcn_mfma_f32_16x16x32_bf16(akh, qlA, (f32x4){0.f,0.f,0.f,0.f}, 0, 0, 0);
        f32x4 svB = __builtin_amdgcn_mfma_f32_16x16x32_bf16(akh, qlB, (f32x4){0.f,0.f,0.f,0.f}, 0, 0, 0);
        svA = __builtin_amdgcn_mfma_f32_16x16x32_bf16(akl, qhA, svA, 0, 0, 0);
        svB = __builtin_amdgcn_mfma_f32_16x16x32_bf16(akl, qhB, svB, 0, 0, 0);
        svA = __builtin_amdgcn_mfma_f32_16x16x32_bf16(akh, qhA, svA, 0, 0, 0);
        svB = __builtin_amdgcn_mfma_f32_16x16x32_bf16(akh, qhB, svB, 0, 0, 0);
        int nA = nbA + c, nB = nbB + c;
#pragma unroll
        for (int r = 0; r < 4; r++) {
            float xA = (nA == mb + 4 * g + r) ? 0.f : svA[r];
            float xB = (nB == mb + 4 * g + r) ? 0.f : svB[r];
            cs[r] += __expf(xA) + __expf(xB);
        }
    }
    // reduce over the 16 c-lanes (lane bits 0..3)
#pragma unroll
    for (int off = 1; off <= 8; off <<= 1) {
#pragma unroll
        for (int r = 0; r < 4; r++) cs[r] += __shfl_xor(cs[r], off, 64);
    }
    if (c == 0) *(f32x4*)&csred[wave][4 * g] = cs;
    __syncthreads();
    f32x4 gs = {0.f, 0.f, 0.f, 0.f};
#pragma unroll
    for (int w = 0; w < 16; w++)
        gs += *(const f32x4*)&csred[w][4 * g];
    f32x4 vinv;
#pragma unroll
    for (int r = 0; r < 4; r++) vinv[r] = 1.0f / gs[r];

    // ---- pass 2: att stores + GEMM2 hv ----
    const ushort_t* vb0 = hkDB + (size_t)(b * HID + c) * KTOT;
    const ushort_t* vb1 = hkDB + (size_t)(b * HID + 16 + c) * KTOT;
    float* attb = att + (size_t)b * KTOT * NN;
    ushort_t (*pt)[40] = PT[wave];

    f32x4 acc0 = {0.f,0.f,0.f,0.f}, acc1 = {0.f,0.f,0.f,0.f};

    for (int ks = 0; ks < 16; ks++) {              // 16 iters, 32 k each
        int k0 = t * NN + nh + ks * 32;            // global k base
#pragma unroll
        for (int half = 0; half < 2; half++) {
            int nb = nh + ks * 32 + half * 16;
            size_t qo = (size_t)(nb + c) * HID + 8 * g;
            bf16x8 qh = *(const bf16x8*)(qhi + qo);
            bf16x8 ql = *(const bf16x8*)(qlo + qo);
            f32x4 sv = __builtin_amdgcn_mfma_f32_16x16x32_bf16(akh, ql, (f32x4){0.f,0.f,0.f,0.f}, 0, 0, 0);
            sv = __builtin_amdgcn_mfma_f32_16x16x32_bf16(akl, qh, sv, 0, 0, 0);
            sv = __builtin_amdgcn_mfma_f32_16x16x32_bf16(akh, qh, sv, 0, 0, 0);
            int n = nb + c;                        // this lane's att row
            float e0, e1, e2, e3;
            {
                float x0 = (n == mb + 4 * g + 0) ? 0.f : sv[0];
                float x1 = (n == mb + 4 * g + 1) ? 0.f : sv[1];
                float x2 = (n == mb + 4 * g + 2) ? 0.f : sv[2];
                float x3 = (n == mb + 4 * g + 3) ? 0.f : sv[3];
                e0 = __expf(x0) * vinv[0];
                e1 = __expf(x1) * vinv[1];
                e2 = __expf(x2) * vinv[2];
                e3 = __expf(x3) * vinv[3];
            }
            f32x4 ev; ev[0] = e0; ev[1] = e1; ev[2] = e2; ev[3] = e3;
            __builtin_nontemporal_store(ev,
                (f32x4*)(attb + (size_t)(t * NN + n) * NN + mb + 4 * g));  // 16B/lane
            int kl = half * 16 + c;
            pt[4 * g + 0][kl] = f2b(e0);
            pt[4 * g + 1][kl] = f2b(e1);
            pt[4 * g + 2][kl] = f2b(e2);
            pt[4 * g + 3][kl] = f2b(e3);
        }
        // GEMM2: hv[m,d] += sum_k P[m,k] * V[k,d]
        bf16x8 pa = *(const bf16x8*)&pt[c][8 * g];        // A2[m=c][k=8g+j]
        bf16x8 v0 = *(const bf16x8*)(vb0 + k0 + 8 * g);   // B2[k][d=c]
        bf16x8 v1 = *(const bf16x8*)(vb1 + k0 + 8 * g);   // B2[k][d=16+c]
        acc0 = __builtin_amdgcn_mfma_f32_16x16x32_bf16(pa, v0, acc0, 0, 0, 0);
        acc1 = __builtin_amdgcn_mfma_f32_16x16x32_bf16(pa, v1, acc1, 0, 0, 0);
    }

    // ---- reduce hv over the 16 waves, write final hv2[b][m][d] ----
#pragma unroll
    for (int r = 0; r < 4; r++) {
        hvred[wave][4 * g + r][c]      = acc0[r];
        hvred[wave][4 * g + r][16 + c] = acc1[r];
    }
    __syncthreads();
    if (tid < 512) {
        int m = tid >> 5, d = tid & 31;
        float s = 0.f;
#pragma unroll
        for (int w = 0; w < 16; w++) s += hvred[w][m][d];
        hv2[((size_t)(b << 10) + mb + m) * HID + d] = s;
    }
}

// ---- out0[b,c,m] = h[b,c,m] + sum_d w_o[c,d] * hv2[b][m][d] ----
__global__ __launch_bounds__(512) void k_out(const float* __restrict__ h,
                                             const float* __restrict__ wo,
                                             const float* __restrict__ hv2,
                                             float* __restrict__ out0) {
    int bx = blockIdx.x;                           // 256: b(4) x mt(64)
    int b = bx >> 6, mt = bx & 63;
    int m0 = mt * 16;
    int tid = threadIdx.x;
    __shared__ float hvL[16][33];
    {
        int mm = tid >> 5, d = tid & 31;           // one value per thread
        hvL[mm][d] = hv2[((size_t)(b << 10) + m0 + mm) * HID + d];  // coalesced
    }
    __syncthreads();
#pragma unroll
    for (int i0 = 0; i0 < 2; i0++) {
        int i = i0 * 512 + tid;
        int c = i >> 4, mm = i & 15;
        float v = h[(size_t)(b * CC + c) * NN + m0 + mm];
#pragma unroll
        for (int d = 0; d < HID; d++) v += wo[c * HID + d] * hvL[mm][d];
        out0[(size_t)(b * CC + c) * NN + m0 + mm] = v;
    }
}

extern "C" void kernel_launch(void* const* d_in, const int* in_sizes, int n_in,
                              void* d_out, int out_size, void* d_ws, size_t ws_size,
                              hipStream_t stream) {
    const float* H   = (const float*)d_in[0];
    const float* h   = (const float*)d_in[1];
    const float* wq  = (const float*)d_in[2];
    const float* wkv = (const float*)d_in[3];
    const float* wo  = (const float*)d_in[4];

    float* out0 = (float*)d_out;                       // [4,64,32,32]
    float* att  = out0 + (size_t)BB * CC * NN;         // [4,8192,1024]

    ushort_t* hqHI  = (ushort_t*)d_ws;                 // 131072
    ushort_t* hqLO  = hqHI  + 131072;                  // 131072
    ushort_t* hkTH0 = hqLO  + 131072;                  // 524288
    ushort_t* hkTH1 = hkTH0 + 524288;                  // 524288
    ushort_t* hkTL0 = hkTH1 + 524288;                  // 524288
    ushort_t* hkTL1 = hkTL0 + 524288;                  // 524288
    ushort_t* hkDB  = hkTL1 + 524288;                  // 1048576
    float* hv2  = (float*)(hkDB + 1048576);            // 131072 f32 (~8 MB total)

    k_pre <<<272, 256,  0, stream>>>(H, h, wq, wkv, hqHI, hqLO,
                                     hkTH0, hkTH1, hkTL0, hkTL1, hkDB);
    k_fuse<<<256, 1024, 0, stream>>>(hqHI, hqLO, hkTH0, hkTH1, hkTL0, hkTL1, hkDB,
                                     att, hv2);
    k_out <<<256, 512,  0, stream>>>(h, wo, hv2, out0);
}

// Round 12
// 85.065 us; speedup vs baseline: 1.2017x; 1.0404x over previous
//
#include <hip/hip_runtime.h>

typedef short bf16x8 __attribute__((ext_vector_type(8)));
typedef float f32x4  __attribute__((ext_vector_type(4)));
typedef unsigned short ushort_t;

#define HID 32
#define CC  64
#define TT  8
#define NN  1024
#define BB  4
#define KTOT 8192

// f32 -> bf16 (RNE)
__device__ __forceinline__ ushort_t f2b(float x) {
    unsigned int u = __float_as_uint(x);
    return (ushort_t)((u + 0x7fffu + ((u >> 16) & 1u)) >> 16);
}
__device__ __forceinline__ float b2f(ushort_t u) {
    return __uint_as_float((unsigned int)u << 16);
}

// --- K1 fused: blocks 0..255 -> hkT planes + hkDB;  blocks 256..271 -> hq hi/lo ---
__global__ __launch_bounds__(256) void k_pre(const float* __restrict__ H,
                                             const float* __restrict__ h,
                                             const float* __restrict__ wq,
                                             const float* __restrict__ wkv,
                                             ushort_t* __restrict__ hqHI,
                                             ushort_t* __restrict__ hqLO,
                                             ushort_t* __restrict__ hkTH0,
                                             ushort_t* __restrict__ hkTH1,
                                             ushort_t* __restrict__ hkTL0,
                                             ushort_t* __restrict__ hkTL1,
                                             ushort_t* __restrict__ hkDB) {
    int bx = blockIdx.x;
    if (bx < 256) {
        int gid = bx * 256 + threadIdx.x;          // 0..65535
        int dg = gid >> 15;                        // block-uniform d-half
        int rest = gid & 32767;
        int b = rest >> 13, tn = rest & 8191;
        int d0 = dg << 4;
        float acc[16];
#pragma unroll
        for (int d = 0; d < 16; d++) acc[d] = 0.f;
        const float* Hb = H + (size_t)(b * CC) * KTOT + tn;
        const float* wb = wkv + d0 * CC;
#pragma unroll 8
        for (int c = 0; c < CC; c++) {
            float v = Hb[(size_t)c * KTOT];        // coalesced
#pragma unroll
            for (int d = 0; d < 16; d++) acc[d] += wb[d * CC + c] * v;  // uniform -> s_load
        }
        ushort_t thi[16], tlo[16];
#pragma unroll
        for (int d = 0; d < 16; d++) {
            ushort_t hi = f2b(acc[d]);
            thi[d] = hi;
            tlo[d] = f2b(acc[d] - b2f(hi));
        }
        size_t po = ((size_t)b * KTOT + tn) * 16;
        bf16x8* ohi = (bf16x8*)((dg ? hkTH1 : hkTH0) + po);
        bf16x8* olo = (bf16x8*)((dg ? hkTL1 : hkTL0) + po);
#pragma unroll
        for (int v8 = 0; v8 < 2; v8++) {
            bf16x8 a, l;
#pragma unroll
            for (int j = 0; j < 8; j++) { a[j] = (short)thi[v8*8+j]; l[j] = (short)tlo[v8*8+j]; }
            ohi[v8] = a; olo[v8] = l;
        }
#pragma unroll
        for (int d = 0; d < 16; d++)
            hkDB[((size_t)(b * HID) + d0 + d) * KTOT + tn] = thi[d];   // coalesced per d
    } else {
        int gid = (bx - 256) * 256 + threadIdx.x;  // 0..4095
        int b = gid >> 10;
        float acc[HID];
#pragma unroll
        for (int d = 0; d < HID; d++) acc[d] = 0.f;
        const float* hb = h + (size_t)(b * CC) * NN + (gid & 1023);
#pragma unroll 4
        for (int c = 0; c < CC; c++) {
            float v = hb[c * NN];                  // coalesced
#pragma unroll
            for (int d = 0; d < HID; d++) acc[d] += wq[d * CC + c] * v;
        }
        bf16x8* ohi = (bf16x8*)(hqHI + (size_t)gid * HID);
        bf16x8* olo = (bf16x8*)(hqLO + (size_t)gid * HID);
#pragma unroll
        for (int v8 = 0; v8 < 4; v8++) {
            bf16x8 thi, tlo;
#pragma unroll
            for (int j = 0; j < 8; j++) {
                float x = acc[v8 * 8 + j];
                ushort_t hi = f2b(x);
                thi[j] = (short)hi;
                tlo[j] = (short)f2b(x - b2f(hi));
            }
            ohi[v8] = thi; olo[v8] = tlo;
        }
    }
}

// ---- Fused: pass1 = bf16 scores -> denom + unnormalized GEMM2 (PT/f2b here);
//      pass2 = hi/lo scores -> exp*vinv -> nontemporal att stores (pure stream) ----
// 256 blocks (XCD-swizzled) = b(4) x mt(64); 16 waves; wave w: t=w>>1, n-half=(w&1)*512.
__global__ __launch_bounds__(1024) void k_fuse(const ushort_t* __restrict__ hqHI,
                                               const ushort_t* __restrict__ hqLO,
                                               const ushort_t* __restrict__ hkTH0,
                                               const ushort_t* __restrict__ hkTH1,
                                               const ushort_t* __restrict__ hkTL0,
                                               const ushort_t* __restrict__ hkTL1,
                                               const ushort_t* __restrict__ hkDB,
                                               float* __restrict__ att,
                                               float* __restrict__ hv2) {
    int bx = blockIdx.x;
    int logical = ((bx & 7) << 5) | (bx >> 3);     // XCD-bijective swizzle (256 = 8 x 32)
    int b = logical >> 6, mt = logical & 63;
    int mb = mt << 4;                              // 16-wide m-tile
    int tid = threadIdx.x;
    int wave = tid >> 6, lane = tid & 63;
    int g = lane >> 4, c = lane & 15;
    int t = wave >> 1;
    int nh = (wave & 1) << 9;                      // n-half base

    __shared__ float csred[16][16];                // [wave][m-local]
    __shared__ float hvred[16][16][32];            // [wave][m-local][d]
    __shared__ __align__(16) ushort_t PT[16][16][40];

    // A frag (loop-invariant): key[mb+c][d] at this t, hi/lo
    size_t ako = ((size_t)b * KTOT + t * NN + (mb + c)) * 16 + (g & 1) * 8;
    bf16x8 akh = *(const bf16x8*)(((g >> 1) ? hkTH1 : hkTH0) + ako);
    bf16x8 akl = *(const bf16x8*)(((g >> 1) ? hkTL1 : hkTL0) + ako);

    const ushort_t* qhi = hqHI + ((size_t)(b << 10)) * HID;
    const ushort_t* qlo = hqLO + ((size_t)(b << 10)) * HID;
    const ushort_t* vb0 = hkDB + (size_t)(b * HID + c) * KTOT;
    const ushort_t* vb1 = hkDB + (size_t)(b * HID + 16 + c) * KTOT;
    ushort_t (*pt)[40] = PT[wave];

    // ---- pass 1: bf16 scores -> e_unnorm; csum; PT transpose; unnormalized GEMM2 ----
    f32x4 cs = {0.f, 0.f, 0.f, 0.f};
    f32x4 acc0 = {0.f,0.f,0.f,0.f}, acc1 = {0.f,0.f,0.f,0.f};
    for (int ks = 0; ks < 16; ks++) {              // 16 iters, 32 k each
        int k0 = t * NN + nh + ks * 32;
#pragma unroll
        for (int half = 0; half < 2; half++) {
            int nb = nh + ks * 32 + half * 16;
            size_t qo = (size_t)(nb + c) * HID + 8 * g;
            bf16x8 qh = *(const bf16x8*)(qhi + qo);
            f32x4 sv = __builtin_amdgcn_mfma_f32_16x16x32_bf16(akh, qh, (f32x4){0.f,0.f,0.f,0.f}, 0, 0, 0);
            int n = nb + c;
            float e0 = __expf((n == mb + 4 * g + 0) ? 0.f : sv[0]);
            float e1 = __expf((n == mb + 4 * g + 1) ? 0.f : sv[1]);
            float e2 = __expf((n == mb + 4 * g + 2) ? 0.f : sv[2]);
            float e3 = __expf((n == mb + 4 * g + 3) ? 0.f : sv[3]);
            cs[0] += e0; cs[1] += e1; cs[2] += e2; cs[3] += e3;
            int kl = half * 16 + c;
            pt[4 * g + 0][kl] = f2b(e0);
            pt[4 * g + 1][kl] = f2b(e1);
            pt[4 * g + 2][kl] = f2b(e2);
            pt[4 * g + 3][kl] = f2b(e3);
        }
        // GEMM2 (unnormalized): hv_u[m,d] += sum_k e[k,m] * V[k,d]
        bf16x8 pa = *(const bf16x8*)&pt[c][8 * g];        // A2[m=c][k=8g+j]
        bf16x8 v0 = *(const bf16x8*)(vb0 + k0 + 8 * g);   // B2[k][d=c]
        bf16x8 v1 = *(const bf16x8*)(vb1 + k0 + 8 * g);   // B2[k][d=16+c]
        acc0 = __builtin_amdgcn_mfma_f32_16x16x32_bf16(pa, v0, acc0, 0, 0, 0);
        acc1 = __builtin_amdgcn_mfma_f32_16x16x32_bf16(pa, v1, acc1, 0, 0, 0);
    }
    // reduce csum over the 16 c-lanes
#pragma unroll
    for (int off = 1; off <= 8; off <<= 1) {
        cs[0] += __shfl_xor(cs[0], off, 64);
        cs[1] += __shfl_xor(cs[1], off, 64);
        cs[2] += __shfl_xor(cs[2], off, 64);
        cs[3] += __shfl_xor(cs[3], off, 64);
    }
    if (c == 0) *(f32x4*)&csred[wave][4 * g] = cs;
    __syncthreads();
    f32x4 gs = {0.f, 0.f, 0.f, 0.f};
#pragma unroll
    for (int w = 0; w < 16; w++)
        gs += *(const f32x4*)&csred[w][4 * g];
    f32x4 vinv;
#pragma unroll
    for (int r = 0; r < 4; r++) vinv[r] = 1.0f / gs[r];

    // scale hv partials by vinv (normalization commutes) and stash
#pragma unroll
    for (int r = 0; r < 4; r++) {
        hvred[wave][4 * g + r][c]      = acc0[r] * vinv[r];
        hvred[wave][4 * g + r][16 + c] = acc1[r] * vinv[r];
    }

    // ---- pass 2: hi/lo scores -> exp*vinv -> att (pure store stream) ----
    float* attb = att + (size_t)b * KTOT * NN;
#pragma unroll 2
    for (int hs = 0; hs < 32; hs++) {
        int nb = nh + hs * 16;
        size_t qo = (size_t)(nb + c) * HID + 8 * g;
        bf16x8 qh = *(const bf16x8*)(qhi + qo);
        bf16x8 ql = *(const bf16x8*)(qlo + qo);
        f32x4 sv = __builtin_amdgcn_mfma_f32_16x16x32_bf16(akh, ql, (f32x4){0.f,0.f,0.f,0.f}, 0, 0, 0);
        sv = __builtin_amdgcn_mfma_f32_16x16x32_bf16(akl, qh, sv, 0, 0, 0);
        sv = __builtin_amdgcn_mfma_f32_16x16x32_bf16(akh, qh, sv, 0, 0, 0);
        int n = nb + c;
        f32x4 ev;
        ev[0] = __expf((n == mb + 4 * g + 0) ? 0.f : sv[0]) * vinv[0];
        ev[1] = __expf((n == mb + 4 * g + 1) ? 0.f : sv[1]) * vinv[1];
        ev[2] = __expf((n == mb + 4 * g + 2) ? 0.f : sv[2]) * vinv[2];
        ev[3] = __expf((n == mb + 4 * g + 3) ? 0.f : sv[3]) * vinv[3];
        __builtin_nontemporal_store(ev,
            (f32x4*)(attb + (size_t)(t * NN + n) * NN + mb + 4 * g));  // 16B/lane
    }

    // ---- reduce hv over the 16 waves, write final hv2[b][m][d] ----
    __syncthreads();
    if (tid < 512) {
        int m = tid >> 5, d = tid & 31;
        float s = 0.f;
#pragma unroll
        for (int w = 0; w < 16; w++) s += hvred[w][m][d];
        hv2[((size_t)(b << 10) + mb + m) * HID + d] = s;
    }
}

// ---- out0[b,c,m] = h[b,c,m] + sum_d w_o[c,d] * hv2[b][m][d] ----
__global__ __launch_bounds__(512) void k_out(const float* __restrict__ h,
                                             const float* __restrict__ wo,
                                             const float* __restrict__ hv2,
                                             float* __restrict__ out0) {
    int bx = blockIdx.x;                           // 256: b(4) x mt(64)
    int b = bx >> 6, mt = bx & 63;
    int m0 = mt * 16;
    int tid = threadIdx.x;
    __shared__ float hvL[16][33];
    {
        int mm = tid >> 5, d = tid & 31;           // one value per thread
        hvL[mm][d] = hv2[((size_t)(b << 10) + m0 + mm) * HID + d];  // coalesced
    }
    __syncthreads();
#pragma unroll
    for (int i0 = 0; i0 < 2; i0++) {
        int i = i0 * 512 + tid;
        int c = i >> 4, mm = i & 15;
        float v = h[(size_t)(b * CC + c) * NN + m0 + mm];
#pragma unroll
        for (int d = 0; d < HID; d++) v += wo[c * HID + d] * hvL[mm][d];
        out0[(size_t)(b * CC + c) * NN + m0 + mm] = v;
    }
}

extern "C" void kernel_launch(void* const* d_in, const int* in_sizes, int n_in,
                              void* d_out, int out_size, void* d_ws, size_t ws_size,
                              hipStream_t stream) {
    const float* H   = (const float*)d_in[0];
    const float* h   = (const float*)d_in[1];
    const float* wq  = (const float*)d_in[2];
    const float* wkv = (const float*)d_in[3];
    const float* wo  = (const float*)d_in[4];

    float* out0 = (float*)d_out;                       // [4,64,32,32]
    float* att  = out0 + (size_t)BB * CC * NN;         // [4,8192,1024]

    ushort_t* hqHI  = (ushort_t*)d_ws;                 // 131072
    ushort_t* hqLO  = hqHI  + 131072;                  // 131072
    ushort_t* hkTH0 = hqLO  + 131072;                  // 524288
    ushort_t* hkTH1 = hkTH0 + 524288;                  // 524288
    ushort_t* hkTL0 = hkTH1 + 524288;                  // 524288
    ushort_t* hkTL1 = hkTL0 + 524288;                  // 524288
    ushort_t* hkDB  = hkTL1 + 524288;                  // 1048576
    float* hv2  = (float*)(hkDB + 1048576);            // 131072 f32 (~8 MB total)

    k_pre <<<272, 256,  0, stream>>>(H, h, wq, wkv, hqHI, hqLO,
                                     hkTH0, hkTH1, hkTL0, hkTL1, hkDB);
    k_fuse<<<256, 1024, 0, stream>>>(hqHI, hqLO, hkTH0, hkTH1, hkTL0, hkTL1, hkDB,
                                     att, hv2);
    k_out <<<256, 512,  0, stream>>>(h, wo, hv2, out0);
}